// Round 1
// baseline (4093.909 us; speedup 1.0000x reference)
//
#include <hip/hip_runtime.h>
#include <math.h>

// Starcoder2 attention, fp32 baseline (round 1: correctness + first counters).
// T=2048, HID=4608, H=36, KV=4, D=128, window=1024.
// Pipeline: QKV GEMM -> RoPE(q,k) -> windowed GQA flash attention -> out GEMM.
// No fp32 MFMA on CDNA4; fp32 vector GEMM for now (bf16-MFMA is the R2 lever).

#define T_SEQ   2048
#define HIDDEN  4608
#define NHEAD   36
#define NKVH    4
#define HEADDIM 128
#define GQA_G   9          // NHEAD / NKVH
#define NQKV    5632       // NHEAD*HEADDIM + 2*NKVH*HEADDIM
#define KOFF    4608
#define VOFF    5120
#define NEG_BIG -1e30f

// ---------------------------------------------------------------------------
// GEMM: C[M,N] = A[M,K] @ B[N,K]^T + bias[N]     (fp32, vector ALU)
// 128x128 block tile, BK=16, 256 threads, 8x8 micro-tile per thread.
// LDS stored k-major ([BK][BM+4]) so fragments are float4 reads; +4 pad keeps
// float4 alignment (132*4 % 16 == 0) and spreads banks.
// ---------------------------------------------------------------------------
__global__ __launch_bounds__(256)
void gemm_bias_kernel(const float* __restrict__ A, const float* __restrict__ B,
                      const float* __restrict__ bias, float* __restrict__ C,
                      int M, int N, int K)
{
    __shared__ float As[16][132];
    __shared__ float Bs[16][132];

    const int tid  = threadIdx.x;
    const int tx   = tid & 15;
    const int ty   = tid >> 4;
    const int row0 = blockIdx.y * 128;
    const int col0 = blockIdx.x * 128;

    // loader: each thread fetches 8 consecutive k of one row (2x float4)
    const int lrow = tid >> 1;
    const int lk   = (tid & 1) * 8;
    const float* Ap = A + (size_t)(row0 + lrow) * K + lk;
    const float* Bp = B + (size_t)(col0 + lrow) * K + lk;

    float acc[8][8];
    #pragma unroll
    for (int i = 0; i < 8; ++i)
        #pragma unroll
        for (int j = 0; j < 8; ++j) acc[i][j] = 0.0f;

    for (int k0 = 0; k0 < K; k0 += 16) {
        float4 a0 = *(const float4*)(Ap);
        float4 a1 = *(const float4*)(Ap + 4);
        float4 b0 = *(const float4*)(Bp);
        float4 b1 = *(const float4*)(Bp + 4);
        Ap += 16; Bp += 16;
        __syncthreads();   // previous iteration's LDS reads must finish
        As[lk + 0][lrow] = a0.x; As[lk + 1][lrow] = a0.y;
        As[lk + 2][lrow] = a0.z; As[lk + 3][lrow] = a0.w;
        As[lk + 4][lrow] = a1.x; As[lk + 5][lrow] = a1.y;
        As[lk + 6][lrow] = a1.z; As[lk + 7][lrow] = a1.w;
        Bs[lk + 0][lrow] = b0.x; Bs[lk + 1][lrow] = b0.y;
        Bs[lk + 2][lrow] = b0.z; Bs[lk + 3][lrow] = b0.w;
        Bs[lk + 4][lrow] = b1.x; Bs[lk + 5][lrow] = b1.y;
        Bs[lk + 6][lrow] = b1.z; Bs[lk + 7][lrow] = b1.w;
        __syncthreads();
        #pragma unroll
        for (int kk = 0; kk < 16; ++kk) {
            float4 av0 = *(const float4*)&As[kk][ty * 4];
            float4 av1 = *(const float4*)&As[kk][64 + ty * 4];
            float4 bv0 = *(const float4*)&Bs[kk][tx * 4];
            float4 bv1 = *(const float4*)&Bs[kk][64 + tx * 4];
            float a_[8] = {av0.x, av0.y, av0.z, av0.w, av1.x, av1.y, av1.z, av1.w};
            float b_[8] = {bv0.x, bv0.y, bv0.z, bv0.w, bv1.x, bv1.y, bv1.z, bv1.w};
            #pragma unroll
            for (int i = 0; i < 8; ++i)
                #pragma unroll
                for (int j = 0; j < 8; ++j)
                    acc[i][j] += a_[i] * b_[j];
        }
    }

    #pragma unroll
    for (int i = 0; i < 8; ++i) {
        const int r = row0 + ((i < 4) ? (ty * 4 + i) : (64 + ty * 4 + (i - 4)));
        float* crow = C + (size_t)r * N;
        #pragma unroll
        for (int jh = 0; jh < 2; ++jh) {
            const int c = col0 + jh * 64 + tx * 4;
            float4 v;
            v.x = acc[i][jh * 4 + 0] + bias[c + 0];
            v.y = acc[i][jh * 4 + 1] + bias[c + 1];
            v.z = acc[i][jh * 4 + 2] + bias[c + 2];
            v.w = acc[i][jh * 4 + 3] + bias[c + 3];
            *(float4*)&crow[c] = v;
        }
    }
}

// ---------------------------------------------------------------------------
// RoPE NeoX, in-place on q (heads 0..35) and k (heads 36..39) in qkv buffer.
// One wave per (t, head); lane d = 0..63 rotates the pair (d, d+64).
// ---------------------------------------------------------------------------
__global__ __launch_bounds__(64)
void rope_kernel(const int* __restrict__ positions, float* __restrict__ qkv)
{
    const int bh   = blockIdx.x;
    const int t    = bh / (NHEAD + NKVH);
    const int head = bh % (NHEAD + NKVH);
    const int d    = threadIdx.x;    // 0..63 = half dim
    float* base = qkv + (size_t)t * NQKV +
                  ((head < NHEAD) ? head * HEADDIM : KOFF + (head - NHEAD) * HEADDIM);
    // inv_freq = THETA^(-d/64), THETA=1e5 ; ln(1e5)=11.512925465
    const float inv_freq = __expf(-(float)d * (11.512925465f / 64.0f));
    const float ang = (float)positions[t] * inv_freq;
    float s, c;
    sincosf(ang, &s, &c);
    const float x1 = base[d];
    const float x2 = base[d + 64];
    base[d]      = x1 * c - x2 * s;
    base[d + 64] = x2 * c + x1 * s;
}

// ---------------------------------------------------------------------------
// Windowed causal GQA flash attention.
// One block (256 thr) per (head, 32-query tile). 32-key tiles, online softmax.
// LDS: Q/K/V tiles 32x(128+4pad) + P tile + row state  (~54 KB -> 2 blocks/CU).
// Thread (qi = tid/8, dc = (tid%8)*16) owns O[qi][dc..dc+15] in registers.
// ---------------------------------------------------------------------------
#define BQ 32
#define BS 32
#define LPAD 132

__global__ __launch_bounds__(256)
void attn_kernel(const float* __restrict__ qkv, float* __restrict__ out,
                 const int* __restrict__ windowp)
{
    __shared__ float Qs[BQ][LPAD];
    __shared__ float Ks[BS][LPAD];
    __shared__ float Vs[BS][LPAD];
    __shared__ float Ss[BQ][BS + 1];
    __shared__ float mrow[BQ], lrow[BQ], arow[BQ];

    const int h   = blockIdx.x;
    const int q0  = blockIdx.y * BQ;
    const int kvh = h / GQA_G;
    const int tid = threadIdx.x;
    const int qi  = tid >> 3;
    const int dc  = (tid & 7) * 16;
    const int window = *windowp;     // device scalar (can't read on host)

    const float scale = 0.088388347648318447f;  // 1/sqrt(128)
    {
        const float* qp = qkv + (size_t)(q0 + qi) * NQKV + h * HEADDIM + dc;
        #pragma unroll
        for (int r = 0; r < 16; r += 4) {
            float4 v = *(const float4*)(qp + r);
            float4 w = make_float4(v.x * scale, v.y * scale, v.z * scale, v.w * scale);
            *(float4*)&Qs[qi][dc + r] = w;
        }
    }
    if (tid < BQ) { mrow[tid] = NEG_BIG; lrow[tid] = 0.0f; }

    float o[16];
    #pragma unroll
    for (int r = 0; r < 16; ++r) o[r] = 0.0f;

    int s_lo = q0 - window + 1;
    if (s_lo < 0) s_lo = 0;
    const int s_start = (s_lo / BS) * BS;
    const int s_end   = q0 + BQ;

    const int sj0 = (tid & 7) * 4;   // score phase: thread does S[qi][sj0..sj0+3]

    for (int st = s_start; st < s_end; st += BS) {
        __syncthreads();             // prev tile's Ks/Vs/Ss reads done
        {
            const float* kp = qkv + (size_t)(st + qi) * NQKV + KOFF + kvh * HEADDIM + dc;
            const float* vp = qkv + (size_t)(st + qi) * NQKV + VOFF + kvh * HEADDIM + dc;
            #pragma unroll
            for (int r = 0; r < 16; r += 4) {
                *(float4*)&Ks[qi][dc + r] = *(const float4*)(kp + r);
                *(float4*)&Vs[qi][dc + r] = *(const float4*)(vp + r);
            }
        }
        __syncthreads();

        // S = (Q*scale) . K^T   (4 scores per thread)
        float sc[4] = {0.f, 0.f, 0.f, 0.f};
        #pragma unroll 4
        for (int d = 0; d < HEADDIM; d += 4) {
            float4 qv = *(const float4*)&Qs[qi][d];
            #pragma unroll
            for (int j = 0; j < 4; ++j) {
                float4 kv = *(const float4*)&Ks[sj0 + j][d];
                sc[j] += qv.x * kv.x + qv.y * kv.y + qv.z * kv.z + qv.w * kv.w;
            }
        }
        const int tg = q0 + qi;
        #pragma unroll
        for (int j = 0; j < 4; ++j) {
            const int s = st + sj0 + j;
            const bool valid = (s <= tg) && (s > tg - window);
            Ss[qi][sj0 + j] = valid ? sc[j] : NEG_BIG;
        }
        __syncthreads();

        // online-softmax row update (32 threads, one row each)
        if (tid < BQ) {
            const float mold = mrow[tid];
            float mx = mold;
            #pragma unroll 8
            for (int s = 0; s < BS; ++s) mx = fmaxf(mx, Ss[tid][s]);
            const float alpha = __expf(mold - mx);  // exp(0)=1 when still all-masked; l=0 keeps O=0
            float sum = 0.0f;
            #pragma unroll 8
            for (int s = 0; s < BS; ++s) {
                const float v = Ss[tid][s];
                const float p = (v > -1e29f) ? __expf(v - mx) : 0.0f; // masked -> exactly 0
                Ss[tid][s] = p;
                sum += p;
            }
            lrow[tid] = lrow[tid] * alpha + sum;
            mrow[tid] = mx;
            arow[tid] = alpha;
        }
        __syncthreads();

        // O = O*alpha + P.V
        const float alpha = arow[qi];
        #pragma unroll
        for (int r = 0; r < 16; ++r) o[r] *= alpha;
        #pragma unroll 2
        for (int s = 0; s < BS; ++s) {
            const float p = Ss[qi][s];
            float4 v0 = *(const float4*)&Vs[s][dc + 0];
            float4 v1 = *(const float4*)&Vs[s][dc + 4];
            float4 v2 = *(const float4*)&Vs[s][dc + 8];
            float4 v3 = *(const float4*)&Vs[s][dc + 12];
            o[0]  += p * v0.x; o[1]  += p * v0.y; o[2]  += p * v0.z; o[3]  += p * v0.w;
            o[4]  += p * v1.x; o[5]  += p * v1.y; o[6]  += p * v1.z; o[7]  += p * v1.w;
            o[8]  += p * v2.x; o[9]  += p * v2.y; o[10] += p * v2.z; o[11] += p * v2.w;
            o[12] += p * v3.x; o[13] += p * v3.y; o[14] += p * v3.z; o[15] += p * v3.w;
        }
    }

    const float inv = 1.0f / lrow[qi];   // s=t always valid => lrow > 0
    float* op = out + (size_t)(q0 + qi) * HIDDEN + h * HEADDIM + dc;
    #pragma unroll
    for (int r = 0; r < 16; r += 4) {
        float4 v = make_float4(o[r] * inv, o[r + 1] * inv, o[r + 2] * inv, o[r + 3] * inv);
        *(float4*)&op[r] = v;
    }
}

// ---------------------------------------------------------------------------
extern "C" void kernel_launch(void* const* d_in, const int* in_sizes, int n_in,
                              void* d_out, int out_size, void* d_ws, size_t ws_size,
                              hipStream_t stream)
{
    const int*   positions = (const int*)d_in[0];
    const float* hidden    = (const float*)d_in[1];
    const float* wqkv      = (const float*)d_in[2];
    const float* bqkv      = (const float*)d_in[3];
    const float* wo        = (const float*)d_in[4];
    const float* bo        = (const float*)d_in[5];
    const int*   windowp   = (const int*)d_in[6];
    float* outp = (float*)d_out;

    // workspace layout: qkv [T,5632] fp32 (46.1 MB) | attn [T,4608] fp32 (37.7 MB)
    float* qkv  = (float*)d_ws;
    float* attn = qkv + (size_t)T_SEQ * NQKV;

    // 1) qkv = hidden @ wqkv^T + bqkv
    gemm_bias_kernel<<<dim3(NQKV / 128, T_SEQ / 128), 256, 0, stream>>>(
        hidden, wqkv, bqkv, qkv, T_SEQ, NQKV, HIDDEN);

    // 2) RoPE on q,k in-place
    rope_kernel<<<T_SEQ * (NHEAD + NKVH), 64, 0, stream>>>(positions, qkv);

    // 3) windowed GQA attention -> attn [T, H*D]
    attn_kernel<<<dim3(NHEAD, T_SEQ / BQ), 256, 0, stream>>>(qkv, attn, windowp);

    // 4) out = attn @ wo^T + bo
    gemm_bias_kernel<<<dim3(HIDDEN / 128, T_SEQ / 128), 256, 0, stream>>>(
        attn, wo, bo, outp, T_SEQ, HIDDEN, HIDDEN);
}